// Round 1
// baseline (681.946 us; speedup 1.0000x reference)
//
#include <hip/hip_runtime.h>

// Problem: B=32768, S=3, D=512, F=512, H=8, DH=64
// Fused: QKV proj (bf16 MFMA) + masked softmax attention (S=3) + out proj.
// Block = 16 batches = 48 rows; 8 waves = 8 heads; 512 threads; 150KB LDS.

typedef __bf16 bf16x8 __attribute__((ext_vector_type(8)));
typedef float f32x4 __attribute__((ext_vector_type(4)));

__device__ __forceinline__ unsigned short f2bf(float f) {
  union { float f; unsigned int u; } v; v.f = f;
  unsigned int u = v.u;
  return (unsigned short)((u + 0x7FFFu + ((u >> 16) & 1u)) >> 16);  // RNE
}
__device__ __forceinline__ float bf2f(unsigned short h) {
  union { unsigned int u; float f; } v; v.u = ((unsigned int)h) << 16;
  return v.f;
}

// ---------------- kernel 0: W[k][n] fp32 -> Wt[n][k] bf16 ----------------
__global__ void __launch_bounds__(256) wtrans(const float* __restrict__ W0,
                                              const float* __restrict__ W1,
                                              const float* __restrict__ W2,
                                              const float* __restrict__ W3,
                                              unsigned short* __restrict__ out) {
  __shared__ float tile[64][65];
  const float* W = (blockIdx.z == 0) ? W0 : (blockIdx.z == 1) ? W1
                   : (blockIdx.z == 2) ? W2 : W3;
  unsigned short* O = out + (size_t)blockIdx.z * 512 * 512;
  int t = threadIdx.x;
  int k0 = blockIdx.x * 64, n0 = blockIdx.y * 64;
#pragma unroll
  for (int i = 0; i < 4; ++i) {
    int r = (t >> 4) + i * 16;
    int c = (t & 15) * 4;
    float4 v = *(const float4*)(W + (k0 + r) * 512 + n0 + c);
    tile[r][c] = v.x; tile[r][c + 1] = v.y; tile[r][c + 2] = v.z; tile[r][c + 3] = v.w;
  }
  __syncthreads();
#pragma unroll
  for (int i = 0; i < 4; ++i) {
    int idx = (t + i * 256) * 4;
    int nr = idx >> 6;
    int kc = idx & 63;
    uint2 pk;
    pk.x = (unsigned int)f2bf(tile[kc][nr]) | ((unsigned int)f2bf(tile[kc + 1][nr]) << 16);
    pk.y = (unsigned int)f2bf(tile[kc + 2][nr]) | ((unsigned int)f2bf(tile[kc + 3][nr]) << 16);
    *(uint2*)(O + (n0 + nr) * 512 + k0 + kc) = pk;
  }
}

// ---------------- fused attention kernel ----------------
// LDS map (bytes):
//   [0      .. 49152)   Aq [48][512] bf16, row-major, XOR-swizzled; later per-wave qh/kh:
//                       wave w: qh at w*12288 ([48][64] sw), kh at w*12288+6144
//                       (qh region reused for attn bf16 after scores)
//   [49152  .. 98304)   Ak [48][512] (second half of per-wave qh/kh regions)
//   [98304  .. 147456)  Av [48][512]; later per-wave vh: 98304 + w*6144, [48][64] UNswizzled
//   [147456 .. 153600)  per-wave scores f32 [48][4]: 147456 + w*768
__device__ __forceinline__ void gemm_proj(char* smem, int abase,
                                          const unsigned short* __restrict__ Bt,
                                          int ncol0, int lr, int lk8, f32x4 acc[3][4]) {
#pragma unroll 4
  for (int ks = 0; ks < 16; ++ks) {
    int kb = ks * 32 + lk8;
    bf16x8 a[3];
#pragma unroll
    for (int mt = 0; mt < 3; ++mt) {
      int row = mt * 16 + lr;
      a[mt] = *(const bf16x8*)(smem + ((abase + row * 1024 + kb * 2) ^ ((row & 7) << 4)));
    }
    bf16x8 b[4];
#pragma unroll
    for (int nt = 0; nt < 4; ++nt)
      b[nt] = *(const bf16x8*)(Bt + (ncol0 + nt * 16 + lr) * 512 + kb);
#pragma unroll
    for (int nt = 0; nt < 4; ++nt) {
#pragma unroll
      for (int mt = 0; mt < 3; ++mt)
        acc[mt][nt] = __builtin_amdgcn_mfma_f32_16x16x32_bf16(a[mt], b[nt], acc[mt][nt], 0, 0, 0);
    }
  }
}

__global__ void __launch_bounds__(512) fused_attn(
    const float* __restrict__ q, const float* __restrict__ kin, const float* __restrict__ vin,
    const int* __restrict__ mask, const unsigned short* __restrict__ wt,
    const float* __restrict__ bq, const float* __restrict__ bk,
    const float* __restrict__ bv, const float* __restrict__ bo,
    float* __restrict__ out) {
  __shared__ alignas(16) char smem[153600];
  const int t = threadIdx.x;
  const int w = t >> 6;            // wave id == head id
  const int l = t & 63;
  const int lr = l & 15;           // fragment row/col index
  const int lk8 = (l >> 4) * 8;    // fragment k base (elements)
  const int lk4 = (l >> 4) * 4;    // C-fragment row base
  const int blk = blockIdx.x;
  const int row0 = blk * 48;
  const int batch0 = blk * 16;

  // ---- phase 0: stage q,k,v rows -> LDS bf16 (swizzled) ----
#pragma unroll
  for (int m = 0; m < 3; ++m) {
    const float* src = (m == 0) ? q : (m == 1) ? kin : vin;
#pragma unroll
    for (int i = 0; i < 12; ++i) {
      int idx = t + i * 512;       // 0..6143  (48 rows x 128 float4)
      int row = idx >> 7;
      int c4 = idx & 127;
      float4 val = *(const float4*)(src + (row0 + row) * 512 + c4 * 4);
      uint2 pk;
      pk.x = (unsigned int)f2bf(val.x) | ((unsigned int)f2bf(val.y) << 16);
      pk.y = (unsigned int)f2bf(val.z) | ((unsigned int)f2bf(val.w) << 16);
      int off = m * 49152 + row * 1024 + c4 * 8;
      *(uint2*)(smem + (off ^ ((row & 7) << 4))) = pk;
    }
  }

  // per-lane bias values (col = w*64 + nt*16 + lr)
  float bqv[4], bkv[4], bvv[4], bov[4];
#pragma unroll
  for (int nt = 0; nt < 4; ++nt) {
    int col = w * 64 + nt * 16 + lr;
    bqv[nt] = bq[col]; bkv[nt] = bk[col]; bvv[nt] = bv[col]; bov[nt] = bo[col];
  }
  __syncthreads();  // B0

  const unsigned short* Wtq = wt;
  const unsigned short* Wtk = wt + 512 * 512;
  const unsigned short* Wtv = wt + 2 * 512 * 512;
  const unsigned short* Wto = wt + 3 * 512 * 512;

  // ---- phase 1: Q and K projections ----
  f32x4 aq[3][4] = {}, ak[3][4] = {};
  gemm_proj(smem, 0, Wtq, w * 64, lr, lk8, aq);
  gemm_proj(smem, 49152, Wtk, w * 64, lr, lk8, ak);
  __syncthreads();  // B1: every wave done reading Aq/Ak

  // write qh (scaled by 1/8, bias folded) and kh into per-wave regions
#pragma unroll
  for (int mt = 0; mt < 3; ++mt)
#pragma unroll
    for (int nt = 0; nt < 4; ++nt)
#pragma unroll
      for (int r = 0; r < 4; ++r) {
        int row = mt * 16 + lk4 + r;
        int d = nt * 16 + lr;
        int sz = (row & 7) << 4;
        *(unsigned short*)(smem + ((w * 12288 + row * 128 + d * 2) ^ sz)) =
            f2bf((aq[mt][nt][r] + bqv[nt]) * 0.125f);
        *(unsigned short*)(smem + ((w * 12288 + 6144 + row * 128 + d * 2) ^ sz)) =
            f2bf(ak[mt][nt][r] + bkv[nt]);
      }

  // ---- phase 2: V projection (Av region untouched by the writes above) ----
  f32x4 av[3][4] = {};
  gemm_proj(smem, 98304, Wtv, w * 64, lr, lk8, av);
  __syncthreads();  // B2: every wave done reading Av

#pragma unroll
  for (int mt = 0; mt < 3; ++mt)
#pragma unroll
    for (int nt = 0; nt < 4; ++nt)
#pragma unroll
      for (int r = 0; r < 4; ++r) {
        int row = mt * 16 + lk4 + r;
        int d = nt * 16 + lr;
        *(unsigned short*)(smem + (98304 + w * 6144 + row * 128 + d * 2)) =
            f2bf(av[mt][nt][r] + bvv[nt]);
      }

  // ---- phase 3: scores = (qh/8) . kh^T   (48x48, keep block-diagonal 3x3) ----
  f32x4 sc[3][3] = {};
#pragma unroll
  for (int ks = 0; ks < 2; ++ks) {
    int kd = ks * 32 + lk8;
    bf16x8 a[3], b[3];
#pragma unroll
    for (int mt = 0; mt < 3; ++mt) {
      int row = mt * 16 + lr;
      int sz = (row & 7) << 4;
      a[mt] = *(const bf16x8*)(smem + ((w * 12288 + row * 128 + kd * 2) ^ sz));
      b[mt] = *(const bf16x8*)(smem + ((w * 12288 + 6144 + row * 128 + kd * 2) ^ sz));
    }
#pragma unroll
    for (int mt = 0; mt < 3; ++mt)
#pragma unroll
      for (int nt = 0; nt < 3; ++nt)
        sc[mt][nt] = __builtin_amdgcn_mfma_f32_16x16x32_bf16(a[mt], b[nt], sc[mt][nt], 0, 0, 0);
  }
#pragma unroll
  for (int mt = 0; mt < 3; ++mt)
#pragma unroll
    for (int nt = 0; nt < 3; ++nt)
#pragma unroll
      for (int r = 0; r < 4; ++r) {
        int qrow = mt * 16 + lk4 + r;
        int krow = nt * 16 + lr;
        int qb = qrow / 3, kb2 = krow / 3;
        if (qb == kb2) {
          int kkk = krow - kb2 * 3;
          *(float*)(smem + (147456 + w * 768 + qrow * 16 + kkk * 4)) = sc[mt][nt][r];
        }
      }

  // ---- phase 4: masked softmax (exact reference fp32 arithmetic) + PV ----
  // lane = head dim d; attn bf16 written into dead qh region (swizzled)
  for (int bi = 0; bi < 16; ++bi) {
    int bg = batch0 + bi;
    float m0 = (float)mask[bg * 3 + 0] * 1e9f;
    float m1 = (float)mask[bg * 3 + 1] * 1e9f;
    float m2 = (float)mask[bg * 3 + 2] * 1e9f;
    float mrow[3] = {m0, m1, m2};
    int vb = 98304 + w * 6144 + bi * 384 + l * 2;
    float v0 = bf2f(*(const unsigned short*)(smem + vb));
    float v1 = bf2f(*(const unsigned short*)(smem + vb + 128));
    float v2 = bf2f(*(const unsigned short*)(smem + vb + 256));
#pragma unroll
    for (int qi = 0; qi < 3; ++qi) {
      const float* srow = (const float*)(smem + (147456 + w * 768 + (bi * 3 + qi) * 16));
      float t0 = (srow[0] - m0) - mrow[qi];
      float t1 = (srow[1] - m1) - mrow[qi];
      float t2 = (srow[2] - m2) - mrow[qi];
      float mx = fmaxf(fmaxf(t0, t1), t2);
      float e0 = __expf(t0 - mx), e1 = __expf(t1 - mx), e2 = __expf(t2 - mx);
      float inv = 1.0f / (e0 + e1 + e2);
      float o = (e0 * v0 + e1 * v1 + e2 * v2) * inv;
      int row = bi * 3 + qi;
      *(unsigned short*)(smem + ((w * 12288 + row * 128 + l * 2) ^ ((row & 7) << 4))) = f2bf(o);
    }
  }
  __syncthreads();  // B3: all heads' attn slices ready

  // ---- phase 5: out = attn @ Wo + bo ----
  f32x4 ao[3][4] = {};
#pragma unroll 4
  for (int ks = 0; ks < 16; ++ks) {
    int kb = ks * 32 + lk8;
    int hk = ks >> 1;        // head region holding k-cols [hk*64, hk*64+64)
    int kd = kb & 63;
    bf16x8 a[3], b[4];
#pragma unroll
    for (int mt = 0; mt < 3; ++mt) {
      int row = mt * 16 + lr;
      a[mt] = *(const bf16x8*)(smem + ((hk * 12288 + row * 128 + kd * 2) ^ ((row & 7) << 4)));
    }
#pragma unroll
    for (int nt = 0; nt < 4; ++nt)
      b[nt] = *(const bf16x8*)(Wto + (w * 64 + nt * 16 + lr) * 512 + kb);
#pragma unroll
    for (int nt = 0; nt < 4; ++nt)
#pragma unroll
      for (int mt = 0; mt < 3; ++mt)
        ao[mt][nt] = __builtin_amdgcn_mfma_f32_16x16x32_bf16(a[mt], b[nt], ao[mt][nt], 0, 0, 0);
  }
#pragma unroll
  for (int mt = 0; mt < 3; ++mt)
#pragma unroll
    for (int nt = 0; nt < 4; ++nt)
#pragma unroll
      for (int r = 0; r < 4; ++r) {
        int grow = row0 + mt * 16 + lk4 + r;
        int col = w * 64 + nt * 16 + lr;
        out[grow * 512 + col] = ao[mt][nt][r] + bov[nt];
      }
}

extern "C" void kernel_launch(void* const* d_in, const int* in_sizes, int n_in,
                              void* d_out, int out_size, void* d_ws, size_t ws_size,
                              hipStream_t stream) {
  const float* q = (const float*)d_in[0];
  const float* k = (const float*)d_in[1];
  const float* v = (const float*)d_in[2];
  const int* mask = (const int*)d_in[3];
  const float* Wq = (const float*)d_in[4];
  const float* bq = (const float*)d_in[5];
  const float* Wk = (const float*)d_in[6];
  const float* bk = (const float*)d_in[7];
  const float* Wv = (const float*)d_in[8];
  const float* bv = (const float*)d_in[9];
  const float* Wo = (const float*)d_in[10];
  const float* bo = (const float*)d_in[11];
  float* out = (float*)d_out;
  unsigned short* wt = (unsigned short*)d_ws;  // 4 x 512x512 bf16 = 2 MB

  wtrans<<<dim3(8, 8, 4), 256, 0, stream>>>(Wq, Wk, Wv, Wo, wt);
  fused_attn<<<2048, 512, 0, stream>>>(q, k, v, mask, wt, bq, bk, bv, bo, out);
}

// Round 2
// 676.887 us; speedup vs baseline: 1.0075x; 1.0075x over previous
//
#include <hip/hip_runtime.h>

// B=32768, S=3, D=512, F=512, H=8, DH=64
// Fused QKV proj + masked softmax attention (S=3) + out proj.
// Block = 16 batches = 48 rows; 8 waves = 8 heads; 512 threads.
// LDS 71872 B -> 2 blocks/CU; __launch_bounds__(512,4) caps VGPR at 128.

typedef __bf16 bf16x8 __attribute__((ext_vector_type(8)));
typedef float f32x4 __attribute__((ext_vector_type(4)));

union U8 { bf16x8 v; unsigned short u[8]; };

__device__ __forceinline__ unsigned short f2bf(float f) {
  union { float f; unsigned int u; } v; v.f = f;
  unsigned int u = v.u;
  return (unsigned short)((u + 0x7FFFu + ((u >> 16) & 1u)) >> 16);  // RNE
}

// ---------------- kernel 0: W[k][n] fp32 -> Wt[n][k] bf16 ----------------
__global__ void __launch_bounds__(256) wtrans(const float* __restrict__ W0,
                                              const float* __restrict__ W1,
                                              const float* __restrict__ W2,
                                              const float* __restrict__ W3,
                                              unsigned short* __restrict__ out) {
  __shared__ float tile[64][65];
  const float* W = (blockIdx.z == 0) ? W0 : (blockIdx.z == 1) ? W1
                   : (blockIdx.z == 2) ? W2 : W3;
  unsigned short* O = out + (size_t)blockIdx.z * 512 * 512;
  int t = threadIdx.x;
  int k0 = blockIdx.x * 64, n0 = blockIdx.y * 64;
#pragma unroll
  for (int i = 0; i < 4; ++i) {
    int r = (t >> 4) + i * 16;
    int c = (t & 15) * 4;
    float4 v = *(const float4*)(W + (k0 + r) * 512 + n0 + c);
    tile[r][c] = v.x; tile[r][c + 1] = v.y; tile[r][c + 2] = v.z; tile[r][c + 3] = v.w;
  }
  __syncthreads();
#pragma unroll
  for (int i = 0; i < 4; ++i) {
    int idx = (t + i * 256) * 4;
    int nr = idx >> 6;
    int kc = idx & 63;
    uint2 pk;
    pk.x = (unsigned int)f2bf(tile[kc][nr]) | ((unsigned int)f2bf(tile[kc + 1][nr]) << 16);
    pk.y = (unsigned int)f2bf(tile[kc + 2][nr]) | ((unsigned int)f2bf(tile[kc + 3][nr]) << 16);
    *(uint2*)(O + (n0 + nr) * 512 + k0 + kc) = pk;
  }
}

// ---------------- fused attention kernel ----------------
// LDS map (bytes):
//   [0     .. 49152)  shared buf [48][512] bf16 swizzled: q -> k -> v -> attn
//   [49152 .. 65536)  per-wave 2 KB tile scratch (16x64 bf16): qh/kh/vhT tiles
//   [65536 .. 71680)  per-wave score scratch [48][4] f32
//   [71680 .. 71872)  masks (48 ints)
#define SH_SCR 49152
#define SH_PS  65536
#define SH_MSK 71680

__device__ __forceinline__ void stage48(const float* __restrict__ src, int row0,
                                        int t, char* smem) {
#pragma unroll
  for (int i = 0; i < 12; ++i) {
    int idx = t + i * 512;             // 48 rows x 128 float4
    int row = idx >> 7;
    int c4 = idx & 127;
    float4 val = *(const float4*)(src + (size_t)(row0 + row) * 512 + c4 * 4);
    uint2 pk;
    pk.x = (unsigned int)f2bf(val.x) | ((unsigned int)f2bf(val.y) << 16);
    pk.y = (unsigned int)f2bf(val.z) | ((unsigned int)f2bf(val.w) << 16);
    int off = row * 1024 + c4 * 8;
    *(uint2*)(smem + (off ^ ((row & 7) << 4))) = pk;
  }
}

__device__ __forceinline__ void gemm_proj(char* smem,
                                          const unsigned short* __restrict__ Bt,
                                          int ncol0, int lr, int lk8, f32x4 acc[3][4]) {
#pragma unroll 4
  for (int ks = 0; ks < 16; ++ks) {
    int kb = ks * 32 + lk8;
    bf16x8 a[3];
#pragma unroll
    for (int mt = 0; mt < 3; ++mt) {
      int row = mt * 16 + lr;
      a[mt] = *(const bf16x8*)(smem + ((row * 1024 + kb * 2) ^ ((row & 7) << 4)));
    }
    bf16x8 b[4];
#pragma unroll
    for (int nt = 0; nt < 4; ++nt)
      b[nt] = *(const bf16x8*)(Bt + (ncol0 + nt * 16 + lr) * 512 + kb);
#pragma unroll
    for (int nt = 0; nt < 4; ++nt) {
#pragma unroll
      for (int mt = 0; mt < 3; ++mt)
        acc[mt][nt] = __builtin_amdgcn_mfma_f32_16x16x32_bf16(a[mt], b[nt], acc[mt][nt], 0, 0, 0);
    }
  }
}

// C-frag tile (16 rows x 64 cols) -> A-frag pair via per-wave 2 KB scratch.
__device__ __forceinline__ void tile_to_afrags(char* scr, const f32x4 acc[4],
                                               const float bias[4], float scale,
                                               int lr, int hi, bf16x8* out) {
#pragma unroll
  for (int nt = 0; nt < 4; ++nt) {
#pragma unroll
    for (int r = 0; r < 4; ++r) {
      int row = 4 * hi + r;
      int col = nt * 16 + lr;
      int addr = (row * 128 + col * 2) ^ ((row & 7) << 4);
      *(unsigned short*)(scr + addr) = f2bf((acc[nt][r] + bias[nt]) * scale);
    }
  }
  asm volatile("s_waitcnt lgkmcnt(0)" ::: "memory");
#pragma unroll
  for (int kb = 0; kb < 2; ++kb) {
    int addr = (lr * 128 + (kb * 32 + hi * 8) * 2) ^ ((lr & 7) << 4);
    out[kb] = *(const bf16x8*)(scr + addr);
  }
  asm volatile("s_waitcnt lgkmcnt(0)" ::: "memory");
}

__global__ void __launch_bounds__(512, 4) fused_attn(
    const float* __restrict__ q, const float* __restrict__ kin, const float* __restrict__ vin,
    const int* __restrict__ mask, const unsigned short* __restrict__ wt,
    const float* __restrict__ bq, const float* __restrict__ bk,
    const float* __restrict__ bv, const float* __restrict__ bo,
    float* __restrict__ out) {
  __shared__ alignas(16) char smem[71872];
  const int t = threadIdx.x;
  const int w = t >> 6;            // wave id == head id
  const int l = t & 63;
  const int lr = l & 15;
  const int hi = l >> 4;
  const int lk8 = hi * 8;
  const int row0 = blockIdx.x * 48;
  const int batch0 = blockIdx.x * 16;
  char* scr = smem + SH_SCR + w * 2048;
  float* pscr = (float*)(smem + SH_PS + w * 768);
  int* maskb = (int*)(smem + SH_MSK);

  if (t < 48) maskb[t] = mask[batch0 * 3 + t];

  float bqv[4], bkv[4], bvv[4], bov[4];
#pragma unroll
  for (int nt = 0; nt < 4; ++nt) {
    int col = w * 64 + nt * 16 + lr;
    bqv[nt] = bq[col]; bkv[nt] = bk[col]; bvv[nt] = bv[col]; bov[nt] = bo[col];
  }

  const unsigned short* Wtq = wt;
  const unsigned short* Wtk = wt + 512 * 512;
  const unsigned short* Wtv = wt + 2 * 512 * 512;
  const unsigned short* Wto = wt + 3 * 512 * 512;

  // ---- stage q, Q-proj, extract qh A-frags (scale 1/8, bias folded) ----
  stage48(q, row0, t, smem);
  __syncthreads();  // B1
  bf16x8 qa[3][2];
  {
    f32x4 aq[3][4] = {};
    gemm_proj(smem, Wtq, w * 64, lr, lk8, aq);
#pragma unroll
    for (int mt = 0; mt < 3; ++mt)
      tile_to_afrags(scr, aq[mt], bqv, 0.125f, lr, hi, qa[mt]);
  }
  __syncthreads();  // B2: all waves done reading staged q

  // ---- stage k, K-proj ----
  stage48(kin, row0, t, smem);
  __syncthreads();  // B3
  f32x4 ack[3][4] = {};
  gemm_proj(smem, Wtk, w * 64, lr, lk8, ack);

  // ---- scores (tile-by-tile kh extraction) + exact-fp32 masked softmax ----
  float p00, p01, p02, p10, p11, p12, p20, p21, p22;
  {
#pragma unroll
    for (int nt = 0; nt < 3; ++nt) {
      bf16x8 kf[2];
      tile_to_afrags(scr, ack[nt], bkv, 1.0f, lr, hi, kf);
      f32x4 s[3] = {};
#pragma unroll
      for (int mt = 0; mt < 3; ++mt) {
        s[mt] = __builtin_amdgcn_mfma_f32_16x16x32_bf16(qa[mt][0], kf[0], s[mt], 0, 0, 0);
        s[mt] = __builtin_amdgcn_mfma_f32_16x16x32_bf16(qa[mt][1], kf[1], s[mt], 0, 0, 0);
      }
      // keep block-diagonal 3x3 per batch
#pragma unroll
      for (int mt = 0; mt < 3; ++mt)
#pragma unroll
        for (int r = 0; r < 4; ++r) {
          int qrow = mt * 16 + hi * 4 + r;
          int krow = nt * 16 + lr;
          int qb = qrow / 3, kb2 = krow / 3;
          if (qb == kb2) pscr[qrow * 4 + (krow - kb2 * 3)] = s[mt][r];
        }
    }
    asm volatile("s_waitcnt lgkmcnt(0)" ::: "memory");
#pragma unroll
    for (int mt = 0; mt < 3; ++mt) {
      int row = mt * 16 + lr;
      int b = row / 3;
      int qi = row - b * 3;
      float s0 = pscr[row * 4 + 0], s1 = pscr[row * 4 + 1], s2 = pscr[row * 4 + 2];
      float m0 = (float)maskb[b * 3 + 0] * 1e9f;
      float m1 = (float)maskb[b * 3 + 1] * 1e9f;
      float m2 = (float)maskb[b * 3 + 2] * 1e9f;
      float mq = (qi == 0) ? m0 : (qi == 1) ? m1 : m2;
      float t0 = (s0 - m0) - mq;
      float t1 = (s1 - m1) - mq;
      float t2 = (s2 - m2) - mq;
      float mx = fmaxf(fmaxf(t0, t1), t2);
      float e0 = __expf(t0 - mx), e1 = __expf(t1 - mx), e2 = __expf(t2 - mx);
      float inv = 1.0f / (e0 + e1 + e2);
      if (mt == 0) { p00 = e0 * inv; p01 = e1 * inv; p02 = e2 * inv; }
      else if (mt == 1) { p10 = e0 * inv; p11 = e1 * inv; p12 = e2 * inv; }
      else { p20 = e0 * inv; p21 = e1 * inv; p22 = e2 * inv; }
    }
  }
  __syncthreads();  // B4: all waves done reading staged k

  // ---- stage v, V-proj ----
  stage48(vin, row0, t, smem);
  __syncthreads();  // B5
  f32x4 acv[3][4] = {};
  gemm_proj(smem, Wtv, w * 64, lr, lk8, acv);

  // ---- vhT extraction (B-frag layout) + P frags + PV MFMA ----
  bf16x8 vb[2][4];
  {
    U8 zz;
#pragma unroll
    for (int e = 0; e < 8; ++e) zz.u[e] = 0;
#pragma unroll
    for (int nt = 0; nt < 4; ++nt) vb[1][nt] = zz.v;
  }
#pragma unroll
  for (int mt = 0; mt < 3; ++mt) {
#pragma unroll
    for (int nt = 0; nt < 4; ++nt) {
      int d = nt * 16 + lr;
      uint2 pk;
      pk.x = (unsigned int)f2bf(acv[mt][nt][0] + bvv[nt]) |
             ((unsigned int)f2bf(acv[mt][nt][1] + bvv[nt]) << 16);
      pk.y = (unsigned int)f2bf(acv[mt][nt][2] + bvv[nt]) |
             ((unsigned int)f2bf(acv[mt][nt][3] + bvv[nt]) << 16);
      *(uint2*)(scr + ((d * 32 + hi * 8) ^ ((d & 1) << 4))) = pk;
    }
    asm volatile("s_waitcnt lgkmcnt(0)" ::: "memory");
#pragma unroll
    for (int nt = 0; nt < 4; ++nt) {
      int d = nt * 16 + lr;
      bf16x8 tmp = *(const bf16x8*)(scr + ((d * 32 + (hi & 1) * 16) ^ ((d & 1) << 4)));
      if (mt == 0)      { if (hi < 2)  vb[0][nt] = tmp; }
      else if (mt == 1) { if (hi >= 2) vb[0][nt] = tmp; }
      else              { if (hi < 2)  vb[1][nt] = tmp; }
    }
    asm volatile("s_waitcnt lgkmcnt(0)" ::: "memory");
  }
  // P A-frags: lane holds P[row=16mt+lr][k=32kb+8hi+e]
  bf16x8 pa[3][2];
#pragma unroll
  for (int mt = 0; mt < 3; ++mt) {
    int row = mt * 16 + lr;
    int b3 = (row / 3) * 3;
#pragma unroll
    for (int kb = 0; kb < 2; ++kb) {
      U8 f;
#pragma unroll
      for (int e = 0; e < 8; ++e) {
        int k = kb * 32 + lk8 + e;
        int j = k - b3;
        float pv_ = 0.f;
        if (j == 0) pv_ = (mt == 0) ? p00 : (mt == 1) ? p10 : p20;
        else if (j == 1) pv_ = (mt == 0) ? p01 : (mt == 1) ? p11 : p21;
        else if (j == 2) pv_ = (mt == 0) ? p02 : (mt == 1) ? p12 : p22;
        f.u[e] = f2bf(pv_);
      }
      pa[mt][kb] = f.v;
    }
  }
  f32x4 pv[3][4] = {};
#pragma unroll
  for (int kb = 0; kb < 2; ++kb)
#pragma unroll
    for (int nt = 0; nt < 4; ++nt)
#pragma unroll
      for (int mt = 0; mt < 3; ++mt)
        pv[mt][nt] = __builtin_amdgcn_mfma_f32_16x16x32_bf16(pa[mt][kb], vb[kb][nt], pv[mt][nt], 0, 0, 0);

  __syncthreads();  // B6: all waves done reading staged v
  // write attn (bf16) into shared buf, full [48][512] swizzled
#pragma unroll
  for (int mt = 0; mt < 3; ++mt)
#pragma unroll
    for (int nt = 0; nt < 4; ++nt)
#pragma unroll
      for (int r = 0; r < 4; ++r) {
        int row = mt * 16 + hi * 4 + r;
        int col = w * 64 + nt * 16 + lr;
        *(unsigned short*)(smem + ((row * 1024 + col * 2) ^ ((row & 7) << 4))) =
            f2bf(pv[mt][nt][r]);
      }
  __syncthreads();  // B7

  // ---- out = attn @ Wo + bo ----
  f32x4 ao[3][4] = {};
  gemm_proj(smem, Wto, w * 64, lr, lk8, ao);
#pragma unroll
  for (int mt = 0; mt < 3; ++mt)
#pragma unroll
    for (int nt = 0; nt < 4; ++nt)
#pragma unroll
      for (int r = 0; r < 4; ++r) {
        int grow = row0 + mt * 16 + hi * 4 + r;
        int col = w * 64 + nt * 16 + lr;
        out[(size_t)grow * 512 + col] = ao[mt][nt][r] + bov[nt];
      }
}

extern "C" void kernel_launch(void* const* d_in, const int* in_sizes, int n_in,
                              void* d_out, int out_size, void* d_ws, size_t ws_size,
                              hipStream_t stream) {
  const float* q = (const float*)d_in[0];
  const float* k = (const float*)d_in[1];
  const float* v = (const float*)d_in[2];
  const int* mask = (const int*)d_in[3];
  const float* Wq = (const float*)d_in[4];
  const float* bq = (const float*)d_in[5];
  const float* Wk = (const float*)d_in[6];
  const float* bk = (const float*)d_in[7];
  const float* Wv = (const float*)d_in[8];
  const float* bv = (const float*)d_in[9];
  const float* Wo = (const float*)d_in[10];
  const float* bo = (const float*)d_in[11];
  float* out = (float*)d_out;
  unsigned short* wt = (unsigned short*)d_ws;  // 4 x 512x512 bf16 = 2 MB

  wtrans<<<dim3(8, 8, 4), 256, 0, stream>>>(Wq, Wk, Wv, Wo, wt);
  fused_attn<<<2048, 512, 0, stream>>>(q, k, v, mask, wt, bq, bk, bv, bo, out);
}

// Round 3
// 504.846 us; speedup vs baseline: 1.3508x; 1.3408x over previous
//
#include <hip/hip_runtime.h>

// B=32768, S=3, D=512, F=512, H=8, DH=64
// Fused QKV proj + masked softmax attention (S=3) + out proj.
// Block = 16 batches = 48 rows; 8 waves = 8 heads; 512 threads.
// LDS 80064 B -> 2 blocks/CU; launch_bounds(512,4) caps unified regs at 128.
// Weights pre-transposed to bf16 in MFMA-fragment order (contiguous 1KB/wave read).

typedef __bf16 bf16x8 __attribute__((ext_vector_type(8)));
typedef float f32x4 __attribute__((ext_vector_type(4)));

union U8 { bf16x8 v; unsigned short u[8]; uint4 q; };

__device__ __forceinline__ unsigned short f2bf(float f) {
  union { float f; unsigned int u; } v; v.f = f;
  unsigned int u = v.u;
  return (unsigned short)((u + 0x7FFFu + ((u >> 16) & 1u)) >> 16);  // RNE
}

// ---- kernel 0: W[k][n] fp32 -> bf16 fragment-ordered ----
// frag addr (shorts): ((n16*16 + ks)*64 + lane)*8 ; content B[n16*16+lr][ks*32+hi*8+e]
__global__ void __launch_bounds__(256) wtrans(const float* __restrict__ W0,
                                              const float* __restrict__ W1,
                                              const float* __restrict__ W2,
                                              const float* __restrict__ W3,
                                              unsigned short* __restrict__ out) {
  __shared__ float tile[64][65];
  const float* W = (blockIdx.z == 0) ? W0 : (blockIdx.z == 1) ? W1
                   : (blockIdx.z == 2) ? W2 : W3;
  unsigned short* O = out + (size_t)blockIdx.z * 512 * 512;
  int t = threadIdx.x;
  int k0 = blockIdx.x * 64, n0 = blockIdx.y * 64;
#pragma unroll
  for (int i = 0; i < 4; ++i) {
    int r = (t >> 4) + i * 16;
    int c = (t & 15) * 4;
    float4 v = *(const float4*)(W + (k0 + r) * 512 + n0 + c);
    tile[r][c] = v.x; tile[r][c + 1] = v.y; tile[r][c + 2] = v.z; tile[r][c + 3] = v.w;
  }
  __syncthreads();
  int lane = t & 63, f = t >> 6;
  int lr = lane & 15, hi = lane >> 4;
#pragma unroll
  for (int i = 0; i < 2; ++i) {
    int g = f + i * 4;          // 0..7
    int n16l = g & 3, ksl = g >> 2;
    U8 pk;
#pragma unroll
    for (int e = 0; e < 8; ++e)
      pk.u[e] = f2bf(tile[ksl * 32 + hi * 8 + e][n16l * 16 + lr]);
    int n16 = (n0 >> 4) + n16l;
    int ksg = (k0 >> 5) + ksl;
    *(uint4*)(O + (((n16 * 16 + ksg) * 64 + lane) * 8)) = pk.q;
  }
}

// ---------------- fused attention kernel ----------------
// LDS map (bytes):
//   [0     .. 49152)  shared buf [48][512] bf16 swizzled: q -> k -> v -> attn
//   [49152 .. 65536)  per-wave 2 KB tile scratch (16x64 bf16)
//   [65536 .. 71680)  per-wave score scratch [48][4] f32
//   [71680 .. 71872)  masks (48 ints)
//   [71872 .. 80064)  bias table f32 [4][512] (q,k,v,o)
#define SH_SCR  49152
#define SH_PS   65536
#define SH_MSK  71680
#define SH_BIAS 71872

__device__ __forceinline__ void stage48(const float* __restrict__ src, int row0,
                                        int t, char* smem) {
#pragma unroll 1
  for (int c = 0; c < 3; ++c) {
    float4 vals[4];
#pragma unroll
    for (int j = 0; j < 4; ++j) {
      int idx = t + (c * 4 + j) * 512;
      int row = idx >> 7, c4 = idx & 127;
      vals[j] = *(const float4*)(src + (size_t)(row0 + row) * 512 + c4 * 4);
    }
#pragma unroll
    for (int j = 0; j < 4; ++j) {
      int idx = t + (c * 4 + j) * 512;
      int row = idx >> 7, c4 = idx & 127;
      uint2 pk;
      pk.x = (unsigned int)f2bf(vals[j].x) | ((unsigned int)f2bf(vals[j].y) << 16);
      pk.y = (unsigned int)f2bf(vals[j].z) | ((unsigned int)f2bf(vals[j].w) << 16);
      *(uint2*)(smem + ((row * 1024 + c4 * 8) ^ ((row & 7) << 4))) = pk;
    }
  }
}

__device__ __forceinline__ void gemm_proj(const char* smem,
                                          const unsigned short* __restrict__ Bt,
                                          int w, int l, int lr, int lk8,
                                          f32x4 acc[3][4]) {
#pragma unroll 4
  for (int ks = 0; ks < 16; ++ks) {
    int kb = ks * 32 + lk8;
    bf16x8 a[3];
#pragma unroll
    for (int mt = 0; mt < 3; ++mt) {
      int row = mt * 16 + lr;
      a[mt] = *(const bf16x8*)(smem + ((row * 1024 + kb * 2) ^ ((row & 7) << 4)));
    }
    bf16x8 b[4];
#pragma unroll
    for (int nt = 0; nt < 4; ++nt)
      b[nt] = *(const bf16x8*)(Bt + (((w * 4 + nt) * 16 + ks) * 64 + l) * 8);
#pragma unroll
    for (int nt = 0; nt < 4; ++nt) {
#pragma unroll
      for (int mt = 0; mt < 3; ++mt)
        acc[mt][nt] = __builtin_amdgcn_mfma_f32_16x16x32_bf16(a[mt], b[nt], acc[mt][nt], 0, 0, 0);
    }
  }
}

// C-frag tile (16 rows x 64 cols) -> A-frag pair via per-wave 2 KB scratch.
// biasp points at bias_row + w*64 + lr; bias for nt = biasp[nt*16].
__device__ __forceinline__ void tile_to_afrags(char* scr, const f32x4 acc[4],
                                               const float* biasp, float scale,
                                               int lr, int hi, bf16x8* out) {
#pragma unroll
  for (int nt = 0; nt < 4; ++nt) {
    float bv = biasp[nt * 16];
#pragma unroll
    for (int r = 0; r < 4; ++r) {
      int row = 4 * hi + r;
      int col = nt * 16 + lr;
      int addr = (row * 128 + col * 2) ^ ((row & 7) << 4);
      *(unsigned short*)(scr + addr) = f2bf((acc[nt][r] + bv) * scale);
    }
  }
  asm volatile("s_waitcnt lgkmcnt(0)" ::: "memory");
#pragma unroll
  for (int kb = 0; kb < 2; ++kb) {
    int addr = (lr * 128 + (kb * 32 + hi * 8) * 2) ^ ((lr & 7) << 4);
    out[kb] = *(const bf16x8*)(scr + addr);
  }
  asm volatile("s_waitcnt lgkmcnt(0)" ::: "memory");
}

__global__ void __launch_bounds__(512, 4) fused_attn(
    const float* __restrict__ q, const float* __restrict__ kin, const float* __restrict__ vin,
    const int* __restrict__ mask, const unsigned short* __restrict__ wt,
    const float* __restrict__ bq, const float* __restrict__ bk,
    const float* __restrict__ bv, const float* __restrict__ bo,
    float* __restrict__ out) {
  __shared__ alignas(16) char smem[80064];
  const int t = threadIdx.x;
  const int w = t >> 6;            // wave id == head id
  const int l = t & 63;
  const int lr = l & 15;
  const int hi = l >> 4;
  const int lk8 = hi * 8;
  const int row0 = blockIdx.x * 48;
  const int batch0 = blockIdx.x * 16;
  char* scr = smem + SH_SCR + w * 2048;
  float* pscr = (float*)(smem + SH_PS + w * 768);
  int* maskb = (int*)(smem + SH_MSK);
  float* biasT = (float*)(smem + SH_BIAS);

  if (t < 48) maskb[t] = mask[batch0 * 3 + t];
  biasT[0 * 512 + t] = bq[t];
  biasT[1 * 512 + t] = bk[t];
  biasT[2 * 512 + t] = bv[t];
  biasT[3 * 512 + t] = bo[t];
  const float* bqp = biasT + 0 * 512 + w * 64 + lr;
  const float* bkp = biasT + 1 * 512 + w * 64 + lr;
  const float* bvp = biasT + 2 * 512 + w * 64 + lr;
  const float* bop = biasT + 3 * 512 + w * 64 + lr;

  const unsigned short* Wtq = wt;
  const unsigned short* Wtk = wt + 512 * 512;
  const unsigned short* Wtv = wt + 2 * 512 * 512;
  const unsigned short* Wto = wt + 3 * 512 * 512;

  // ---- stage q, Q-proj, extract qh A-frags (scale 1/8, bias folded) ----
  stage48(q, row0, t, smem);
  __syncthreads();  // B1
  bf16x8 qa[3][2];
  {
    f32x4 aq[3][4] = {};
    gemm_proj(smem, Wtq, w, l, lr, lk8, aq);
#pragma unroll
    for (int mt = 0; mt < 3; ++mt)
      tile_to_afrags(scr, aq[mt], bqp, 0.125f, lr, hi, qa[mt]);
  }
  __syncthreads();  // B2: all waves done reading staged q

  // ---- stage k, K-proj ----
  stage48(kin, row0, t, smem);
  __syncthreads();  // B3
  f32x4 ack[3][4] = {};
  gemm_proj(smem, Wtk, w, l, lr, lk8, ack);

  // ---- scores (tile-by-tile kh extraction) + exact-fp32 masked softmax ----
  float p00, p01, p02, p10, p11, p12, p20, p21, p22;
  {
#pragma unroll
    for (int nt = 0; nt < 3; ++nt) {
      bf16x8 kf[2];
      tile_to_afrags(scr, ack[nt], bkp, 1.0f, lr, hi, kf);
      f32x4 s[3] = {};
#pragma unroll
      for (int mt = 0; mt < 3; ++mt) {
        s[mt] = __builtin_amdgcn_mfma_f32_16x16x32_bf16(qa[mt][0], kf[0], s[mt], 0, 0, 0);
        s[mt] = __builtin_amdgcn_mfma_f32_16x16x32_bf16(qa[mt][1], kf[1], s[mt], 0, 0, 0);
      }
#pragma unroll
      for (int mt = 0; mt < 3; ++mt)
#pragma unroll
        for (int r = 0; r < 4; ++r) {
          int qrow = mt * 16 + hi * 4 + r;
          int krow = nt * 16 + lr;
          int qb = qrow / 3, kb2 = krow / 3;
          if (qb == kb2) pscr[qrow * 4 + (krow - kb2 * 3)] = s[mt][r];
        }
    }
    asm volatile("s_waitcnt lgkmcnt(0)" ::: "memory");
#pragma unroll
    for (int mt = 0; mt < 3; ++mt) {
      int row = mt * 16 + lr;
      int b = row / 3;
      int qi = row - b * 3;
      float s0 = pscr[row * 4 + 0], s1 = pscr[row * 4 + 1], s2 = pscr[row * 4 + 2];
      float m0 = (float)maskb[b * 3 + 0] * 1e9f;
      float m1 = (float)maskb[b * 3 + 1] * 1e9f;
      float m2 = (float)maskb[b * 3 + 2] * 1e9f;
      float mq = (qi == 0) ? m0 : (qi == 1) ? m1 : m2;
      float t0 = (s0 - m0) - mq;
      float t1 = (s1 - m1) - mq;
      float t2 = (s2 - m2) - mq;
      float mx = fmaxf(fmaxf(t0, t1), t2);
      float e0 = __expf(t0 - mx), e1 = __expf(t1 - mx), e2 = __expf(t2 - mx);
      float inv = 1.0f / (e0 + e1 + e2);
      if (mt == 0) { p00 = e0 * inv; p01 = e1 * inv; p02 = e2 * inv; }
      else if (mt == 1) { p10 = e0 * inv; p11 = e1 * inv; p12 = e2 * inv; }
      else { p20 = e0 * inv; p21 = e1 * inv; p22 = e2 * inv; }
    }
  }
  __syncthreads();  // B4: all waves done reading staged k

  // ---- stage v, V-proj ----
  stage48(vin, row0, t, smem);
  __syncthreads();  // B5
  f32x4 acv[3][4] = {};
  gemm_proj(smem, Wtv, w, l, lr, lk8, acv);

  // ---- vhT extraction (B-frag layout) + P frags + PV MFMA ----
  bf16x8 vb2[2][4];
  {
    U8 zz;
#pragma unroll
    for (int e = 0; e < 8; ++e) zz.u[e] = 0;
#pragma unroll
    for (int nt = 0; nt < 4; ++nt) vb2[1][nt] = zz.v;
  }
#pragma unroll
  for (int mt = 0; mt < 3; ++mt) {
#pragma unroll
    for (int nt = 0; nt < 4; ++nt) {
      float bvl = bvp[nt * 16];
      int d = nt * 16 + lr;
      uint2 pk;
      pk.x = (unsigned int)f2bf(acv[mt][nt][0] + bvl) |
             ((unsigned int)f2bf(acv[mt][nt][1] + bvl) << 16);
      pk.y = (unsigned int)f2bf(acv[mt][nt][2] + bvl) |
             ((unsigned int)f2bf(acv[mt][nt][3] + bvl) << 16);
      *(uint2*)(scr + ((d * 32 + hi * 8) ^ ((d & 1) << 4))) = pk;
    }
    asm volatile("s_waitcnt lgkmcnt(0)" ::: "memory");
#pragma unroll
    for (int nt = 0; nt < 4; ++nt) {
      int d = nt * 16 + lr;
      bf16x8 tmp = *(const bf16x8*)(scr + ((d * 32 + (hi & 1) * 16) ^ ((d & 1) << 4)));
      if (mt == 0)      { if (hi < 2)  vb2[0][nt] = tmp; }
      else if (mt == 1) { if (hi >= 2) vb2[0][nt] = tmp; }
      else              { if (hi < 2)  vb2[1][nt] = tmp; }
    }
    asm volatile("s_waitcnt lgkmcnt(0)" ::: "memory");
  }
  // P A-frags: lane holds P[row=16mt+lr][k=32kb+8hi+e]
  bf16x8 pa[3][2];
#pragma unroll
  for (int mt = 0; mt < 3; ++mt) {
    int row = mt * 16 + lr;
    int b3 = (row / 3) * 3;
#pragma unroll
    for (int kb = 0; kb < 2; ++kb) {
      U8 f;
#pragma unroll
      for (int e = 0; e < 8; ++e) {
        int k = kb * 32 + lk8 + e;
        int j = k - b3;
        float pv_ = 0.f;
        if (j == 0) pv_ = (mt == 0) ? p00 : (mt == 1) ? p10 : p20;
        else if (j == 1) pv_ = (mt == 0) ? p01 : (mt == 1) ? p11 : p21;
        else if (j == 2) pv_ = (mt == 0) ? p02 : (mt == 1) ? p12 : p22;
        f.u[e] = f2bf(pv_);
      }
      pa[mt][kb] = f.v;
    }
  }
  f32x4 pv[3][4] = {};
#pragma unroll
  for (int kb = 0; kb < 2; ++kb)
#pragma unroll
    for (int nt = 0; nt < 4; ++nt)
#pragma unroll
      for (int mt = 0; mt < 3; ++mt)
        pv[mt][nt] = __builtin_amdgcn_mfma_f32_16x16x32_bf16(pa[mt][kb], vb2[kb][nt], pv[mt][nt], 0, 0, 0);

  __syncthreads();  // B6: all waves done reading staged v
  // write attn (bf16) into shared buf, full [48][512] swizzled
#pragma unroll
  for (int mt = 0; mt < 3; ++mt)
#pragma unroll
    for (int nt = 0; nt < 4; ++nt)
#pragma unroll
      for (int r = 0; r < 4; ++r) {
        int row = mt * 16 + hi * 4 + r;
        int col = w * 64 + nt * 16 + lr;
        *(unsigned short*)(smem + ((row * 1024 + col * 2) ^ ((row & 7) << 4))) =
            f2bf(pv[mt][nt][r]);
      }
  __syncthreads();  // B7

  // ---- out = attn @ Wo + bo ----
  f32x4 ao[3][4] = {};
  gemm_proj(smem, Wto, w, l, lr, lk8, ao);
#pragma unroll
  for (int mt = 0; mt < 3; ++mt)
#pragma unroll
    for (int nt = 0; nt < 4; ++nt) {
      float bvo = bop[nt * 16];
#pragma unroll
      for (int r = 0; r < 4; ++r) {
        int grow = row0 + mt * 16 + hi * 4 + r;
        int col = w * 64 + nt * 16 + lr;
        out[(size_t)grow * 512 + col] = ao[mt][nt][r] + bvo;
      }
    }
}

extern "C" void kernel_launch(void* const* d_in, const int* in_sizes, int n_in,
                              void* d_out, int out_size, void* d_ws, size_t ws_size,
                              hipStream_t stream) {
  const float* q = (const float*)d_in[0];
  const float* k = (const float*)d_in[1];
  const float* v = (const float*)d_in[2];
  const int* mask = (const int*)d_in[3];
  const float* Wq = (const float*)d_in[4];
  const float* bq = (const float*)d_in[5];
  const float* Wk = (const float*)d_in[6];
  const float* bk = (const float*)d_in[7];
  const float* Wv = (const float*)d_in[8];
  const float* bv = (const float*)d_in[9];
  const float* Wo = (const float*)d_in[10];
  const float* bo = (const float*)d_in[11];
  float* out = (float*)d_out;
  unsigned short* wt = (unsigned short*)d_ws;  // 4 x 512x512 bf16 = 2 MB

  wtrans<<<dim3(8, 8, 4), 256, 0, stream>>>(Wq, Wk, Wv, Wo, wt);
  fused_attn<<<2048, 512, 0, stream>>>(q, k, v, mask, wt, bq, bk, bv, bo, out);
}

// Round 4
// 419.512 us; speedup vs baseline: 1.6256x; 1.2034x over previous
//
#include <hip/hip_runtime.h>

// B=32768, S=3, D=512, F=512, H=8, DH=64
// Fused QKV proj + masked softmax attention (S=3) + out proj.
// Block = 16 batches = 48 rows; 8 waves = 8 heads; 512 threads.
// LDS 80064 B -> 2 blocks/CU; launch_bounds(512,4) caps unified regs at 128.
// Weights pre-transposed to bf16 in MFMA-fragment order (contiguous 1KB/wave read).
// R4: gemm_proj unroll 4 -> 2 (B-prefetch window 64->32 regs) to kill scratch spills.

typedef __bf16 bf16x8 __attribute__((ext_vector_type(8)));
typedef float f32x4 __attribute__((ext_vector_type(4)));

union U8 { bf16x8 v; unsigned short u[8]; uint4 q; };

__device__ __forceinline__ unsigned short f2bf(float f) {
  union { float f; unsigned int u; } v; v.f = f;
  unsigned int u = v.u;
  return (unsigned short)((u + 0x7FFFu + ((u >> 16) & 1u)) >> 16);  // RNE
}

// ---- kernel 0: W[k][n] fp32 -> bf16 fragment-ordered ----
// frag addr (shorts): ((n16*16 + ks)*64 + lane)*8 ; content B[n16*16+lr][ks*32+hi*8+e]
__global__ void __launch_bounds__(256) wtrans(const float* __restrict__ W0,
                                              const float* __restrict__ W1,
                                              const float* __restrict__ W2,
                                              const float* __restrict__ W3,
                                              unsigned short* __restrict__ out) {
  __shared__ float tile[64][65];
  const float* W = (blockIdx.z == 0) ? W0 : (blockIdx.z == 1) ? W1
                   : (blockIdx.z == 2) ? W2 : W3;
  unsigned short* O = out + (size_t)blockIdx.z * 512 * 512;
  int t = threadIdx.x;
  int k0 = blockIdx.x * 64, n0 = blockIdx.y * 64;
#pragma unroll
  for (int i = 0; i < 4; ++i) {
    int r = (t >> 4) + i * 16;
    int c = (t & 15) * 4;
    float4 v = *(const float4*)(W + (k0 + r) * 512 + n0 + c);
    tile[r][c] = v.x; tile[r][c + 1] = v.y; tile[r][c + 2] = v.z; tile[r][c + 3] = v.w;
  }
  __syncthreads();
  int lane = t & 63, f = t >> 6;
  int lr = lane & 15, hi = lane >> 4;
#pragma unroll
  for (int i = 0; i < 2; ++i) {
    int g = f + i * 4;          // 0..7
    int n16l = g & 3, ksl = g >> 2;
    U8 pk;
#pragma unroll
    for (int e = 0; e < 8; ++e)
      pk.u[e] = f2bf(tile[ksl * 32 + hi * 8 + e][n16l * 16 + lr]);
    int n16 = (n0 >> 4) + n16l;
    int ksg = (k0 >> 5) + ksl;
    *(uint4*)(O + (((n16 * 16 + ksg) * 64 + lane) * 8)) = pk.q;
  }
}

// ---------------- fused attention kernel ----------------
// LDS map (bytes):
//   [0     .. 49152)  shared buf [48][512] bf16 swizzled: q -> k -> v -> attn
//   [49152 .. 65536)  per-wave 2 KB tile scratch (16x64 bf16)
//   [65536 .. 71680)  per-wave score scratch [48][4] f32
//   [71680 .. 71872)  masks (48 ints)
//   [71872 .. 80064)  bias table f32 [4][512] (q,k,v,o)
#define SH_SCR  49152
#define SH_PS   65536
#define SH_MSK  71680
#define SH_BIAS 71872

__device__ __forceinline__ void stage48(const float* __restrict__ src, int row0,
                                        int t, char* smem) {
#pragma unroll 1
  for (int c = 0; c < 3; ++c) {
    float4 vals[4];
#pragma unroll
    for (int j = 0; j < 4; ++j) {
      int idx = t + (c * 4 + j) * 512;
      int row = idx >> 7, c4 = idx & 127;
      vals[j] = *(const float4*)(src + (size_t)(row0 + row) * 512 + c4 * 4);
    }
#pragma unroll
    for (int j = 0; j < 4; ++j) {
      int idx = t + (c * 4 + j) * 512;
      int row = idx >> 7, c4 = idx & 127;
      uint2 pk;
      pk.x = (unsigned int)f2bf(vals[j].x) | ((unsigned int)f2bf(vals[j].y) << 16);
      pk.y = (unsigned int)f2bf(vals[j].z) | ((unsigned int)f2bf(vals[j].w) << 16);
      *(uint2*)(smem + ((row * 1024 + c4 * 8) ^ ((row & 7) << 4))) = pk;
    }
  }
}

__device__ __forceinline__ void gemm_proj(const char* smem,
                                          const unsigned short* __restrict__ Bt,
                                          int w, int l, int lr, int lk8,
                                          f32x4 acc[3][4]) {
#pragma unroll 2
  for (int ks = 0; ks < 16; ++ks) {
    int kb = ks * 32 + lk8;
    bf16x8 a[3];
#pragma unroll
    for (int mt = 0; mt < 3; ++mt) {
      int row = mt * 16 + lr;
      a[mt] = *(const bf16x8*)(smem + ((row * 1024 + kb * 2) ^ ((row & 7) << 4)));
    }
    bf16x8 b[4];
#pragma unroll
    for (int nt = 0; nt < 4; ++nt)
      b[nt] = *(const bf16x8*)(Bt + (((w * 4 + nt) * 16 + ks) * 64 + l) * 8);
#pragma unroll
    for (int nt = 0; nt < 4; ++nt) {
#pragma unroll
      for (int mt = 0; mt < 3; ++mt)
        acc[mt][nt] = __builtin_amdgcn_mfma_f32_16x16x32_bf16(a[mt], b[nt], acc[mt][nt], 0, 0, 0);
    }
  }
}

// C-frag tile (16 rows x 64 cols) -> A-frag pair via per-wave 2 KB scratch.
// biasp points at bias_row + w*64 + lr; bias for nt = biasp[nt*16].
__device__ __forceinline__ void tile_to_afrags(char* scr, const f32x4 acc[4],
                                               const float* biasp, float scale,
                                               int lr, int hi, bf16x8* out) {
#pragma unroll
  for (int nt = 0; nt < 4; ++nt) {
    float bv = biasp[nt * 16];
#pragma unroll
    for (int r = 0; r < 4; ++r) {
      int row = 4 * hi + r;
      int col = nt * 16 + lr;
      int addr = (row * 128 + col * 2) ^ ((row & 7) << 4);
      *(unsigned short*)(scr + addr) = f2bf((acc[nt][r] + bv) * scale);
    }
  }
  asm volatile("s_waitcnt lgkmcnt(0)" ::: "memory");
#pragma unroll
  for (int kb = 0; kb < 2; ++kb) {
    int addr = (lr * 128 + (kb * 32 + hi * 8) * 2) ^ ((lr & 7) << 4);
    out[kb] = *(const bf16x8*)(scr + addr);
  }
  asm volatile("s_waitcnt lgkmcnt(0)" ::: "memory");
}

__global__ void __launch_bounds__(512, 4) fused_attn(
    const float* __restrict__ q, const float* __restrict__ kin, const float* __restrict__ vin,
    const int* __restrict__ mask, const unsigned short* __restrict__ wt,
    const float* __restrict__ bq, const float* __restrict__ bk,
    const float* __restrict__ bv, const float* __restrict__ bo,
    float* __restrict__ out) {
  __shared__ alignas(16) char smem[80064];
  const int t = threadIdx.x;
  const int w = t >> 6;            // wave id == head id
  const int l = t & 63;
  const int lr = l & 15;
  const int hi = l >> 4;
  const int lk8 = hi * 8;
  const int row0 = blockIdx.x * 48;
  const int batch0 = blockIdx.x * 16;
  char* scr = smem + SH_SCR + w * 2048;
  float* pscr = (float*)(smem + SH_PS + w * 768);
  int* maskb = (int*)(smem + SH_MSK);
  float* biasT = (float*)(smem + SH_BIAS);

  if (t < 48) maskb[t] = mask[batch0 * 3 + t];
  biasT[0 * 512 + t] = bq[t];
  biasT[1 * 512 + t] = bk[t];
  biasT[2 * 512 + t] = bv[t];
  biasT[3 * 512 + t] = bo[t];
  const float* bqp = biasT + 0 * 512 + w * 64 + lr;
  const float* bkp = biasT + 1 * 512 + w * 64 + lr;
  const float* bvp = biasT + 2 * 512 + w * 64 + lr;
  const float* bop = biasT + 3 * 512 + w * 64 + lr;

  const unsigned short* Wtq = wt;
  const unsigned short* Wtk = wt + 512 * 512;
  const unsigned short* Wtv = wt + 2 * 512 * 512;
  const unsigned short* Wto = wt + 3 * 512 * 512;

  // ---- stage q, Q-proj, extract qh A-frags (scale 1/8, bias folded) ----
  stage48(q, row0, t, smem);
  __syncthreads();  // B1
  bf16x8 qa[3][2];
  {
    f32x4 aq[3][4] = {};
    gemm_proj(smem, Wtq, w, l, lr, lk8, aq);
#pragma unroll
    for (int mt = 0; mt < 3; ++mt)
      tile_to_afrags(scr, aq[mt], bqp, 0.125f, lr, hi, qa[mt]);
  }
  __syncthreads();  // B2: all waves done reading staged q

  // ---- stage k, K-proj ----
  stage48(kin, row0, t, smem);
  __syncthreads();  // B3
  f32x4 ack[3][4] = {};
  gemm_proj(smem, Wtk, w, l, lr, lk8, ack);

  // ---- scores (tile-by-tile kh extraction) + exact-fp32 masked softmax ----
  float p00, p01, p02, p10, p11, p12, p20, p21, p22;
  {
#pragma unroll
    for (int nt = 0; nt < 3; ++nt) {
      bf16x8 kf[2];
      tile_to_afrags(scr, ack[nt], bkp, 1.0f, lr, hi, kf);
      f32x4 s[3] = {};
#pragma unroll
      for (int mt = 0; mt < 3; ++mt) {
        s[mt] = __builtin_amdgcn_mfma_f32_16x16x32_bf16(qa[mt][0], kf[0], s[mt], 0, 0, 0);
        s[mt] = __builtin_amdgcn_mfma_f32_16x16x32_bf16(qa[mt][1], kf[1], s[mt], 0, 0, 0);
      }
#pragma unroll
      for (int mt = 0; mt < 3; ++mt)
#pragma unroll
        for (int r = 0; r < 4; ++r) {
          int qrow = mt * 16 + hi * 4 + r;
          int krow = nt * 16 + lr;
          int qb = qrow / 3, kb2 = krow / 3;
          if (qb == kb2) pscr[qrow * 4 + (krow - kb2 * 3)] = s[mt][r];
        }
    }
    asm volatile("s_waitcnt lgkmcnt(0)" ::: "memory");
#pragma unroll
    for (int mt = 0; mt < 3; ++mt) {
      int row = mt * 16 + lr;
      int b = row / 3;
      int qi = row - b * 3;
      float s0 = pscr[row * 4 + 0], s1 = pscr[row * 4 + 1], s2 = pscr[row * 4 + 2];
      float m0 = (float)maskb[b * 3 + 0] * 1e9f;
      float m1 = (float)maskb[b * 3 + 1] * 1e9f;
      float m2 = (float)maskb[b * 3 + 2] * 1e9f;
      float mq = (qi == 0) ? m0 : (qi == 1) ? m1 : m2;
      float t0 = (s0 - m0) - mq;
      float t1 = (s1 - m1) - mq;
      float t2 = (s2 - m2) - mq;
      float mx = fmaxf(fmaxf(t0, t1), t2);
      float e0 = __expf(t0 - mx), e1 = __expf(t1 - mx), e2 = __expf(t2 - mx);
      float inv = 1.0f / (e0 + e1 + e2);
      if (mt == 0) { p00 = e0 * inv; p01 = e1 * inv; p02 = e2 * inv; }
      else if (mt == 1) { p10 = e0 * inv; p11 = e1 * inv; p12 = e2 * inv; }
      else { p20 = e0 * inv; p21 = e1 * inv; p22 = e2 * inv; }
    }
  }
  __syncthreads();  // B4: all waves done reading staged k

  // ---- stage v, V-proj ----
  stage48(vin, row0, t, smem);
  __syncthreads();  // B5
  f32x4 acv[3][4] = {};
  gemm_proj(smem, Wtv, w, l, lr, lk8, acv);

  // ---- vhT extraction (B-frag layout) + P frags + PV MFMA ----
  bf16x8 vb2[2][4];
  {
    U8 zz;
#pragma unroll
    for (int e = 0; e < 8; ++e) zz.u[e] = 0;
#pragma unroll
    for (int nt = 0; nt < 4; ++nt) vb2[1][nt] = zz.v;
  }
#pragma unroll
  for (int mt = 0; mt < 3; ++mt) {
#pragma unroll
    for (int nt = 0; nt < 4; ++nt) {
      float bvl = bvp[nt * 16];
      int d = nt * 16 + lr;
      uint2 pk;
      pk.x = (unsigned int)f2bf(acv[mt][nt][0] + bvl) |
             ((unsigned int)f2bf(acv[mt][nt][1] + bvl) << 16);
      pk.y = (unsigned int)f2bf(acv[mt][nt][2] + bvl) |
             ((unsigned int)f2bf(acv[mt][nt][3] + bvl) << 16);
      *(uint2*)(scr + ((d * 32 + hi * 8) ^ ((d & 1) << 4))) = pk;
    }
    asm volatile("s_waitcnt lgkmcnt(0)" ::: "memory");
#pragma unroll
    for (int nt = 0; nt < 4; ++nt) {
      int d = nt * 16 + lr;
      bf16x8 tmp = *(const bf16x8*)(scr + ((d * 32 + (hi & 1) * 16) ^ ((d & 1) << 4)));
      if (mt == 0)      { if (hi < 2)  vb2[0][nt] = tmp; }
      else if (mt == 1) { if (hi >= 2) vb2[0][nt] = tmp; }
      else              { if (hi < 2)  vb2[1][nt] = tmp; }
    }
    asm volatile("s_waitcnt lgkmcnt(0)" ::: "memory");
  }
  // P A-frags: lane holds P[row=16mt+lr][k=32kb+8hi+e]
  bf16x8 pa[3][2];
#pragma unroll
  for (int mt = 0; mt < 3; ++mt) {
    int row = mt * 16 + lr;
    int b3 = (row / 3) * 3;
#pragma unroll
    for (int kb = 0; kb < 2; ++kb) {
      U8 f;
#pragma unroll
      for (int e = 0; e < 8; ++e) {
        int k = kb * 32 + lk8 + e;
        int j = k - b3;
        float pv_ = 0.f;
        if (j == 0) pv_ = (mt == 0) ? p00 : (mt == 1) ? p10 : p20;
        else if (j == 1) pv_ = (mt == 0) ? p01 : (mt == 1) ? p11 : p21;
        else if (j == 2) pv_ = (mt == 0) ? p02 : (mt == 1) ? p12 : p22;
        f.u[e] = f2bf(pv_);
      }
      pa[mt][kb] = f.v;
    }
  }
  f32x4 pv[3][4] = {};
#pragma unroll
  for (int kb = 0; kb < 2; ++kb)
#pragma unroll
    for (int nt = 0; nt < 4; ++nt)
#pragma unroll
      for (int mt = 0; mt < 3; ++mt)
        pv[mt][nt] = __builtin_amdgcn_mfma_f32_16x16x32_bf16(pa[mt][kb], vb2[kb][nt], pv[mt][nt], 0, 0, 0);

  __syncthreads();  // B6: all waves done reading staged v
  // write attn (bf16) into shared buf, full [48][512] swizzled
#pragma unroll
  for (int mt = 0; mt < 3; ++mt)
#pragma unroll
    for (int nt = 0; nt < 4; ++nt)
#pragma unroll
      for (int r = 0; r < 4; ++r) {
        int row = mt * 16 + hi * 4 + r;
        int col = w * 64 + nt * 16 + lr;
        *(unsigned short*)(smem + ((row * 1024 + col * 2) ^ ((row & 7) << 4))) =
            f2bf(pv[mt][nt][r]);
      }
  __syncthreads();  // B7

  // ---- out = attn @ Wo + bo ----
  f32x4 ao[3][4] = {};
  gemm_proj(smem, Wto, w, l, lr, lk8, ao);
#pragma unroll
  for (int mt = 0; mt < 3; ++mt)
#pragma unroll
    for (int nt = 0; nt < 4; ++nt) {
      float bvo = bop[nt * 16];
#pragma unroll
      for (int r = 0; r < 4; ++r) {
        int grow = row0 + mt * 16 + hi * 4 + r;
        int col = w * 64 + nt * 16 + lr;
        out[(size_t)grow * 512 + col] = ao[mt][nt][r] + bvo;
      }
    }
}

extern "C" void kernel_launch(void* const* d_in, const int* in_sizes, int n_in,
                              void* d_out, int out_size, void* d_ws, size_t ws_size,
                              hipStream_t stream) {
  const float* q = (const float*)d_in[0];
  const float* k = (const float*)d_in[1];
  const float* v = (const float*)d_in[2];
  const int* mask = (const int*)d_in[3];
  const float* Wq = (const float*)d_in[4];
  const float* bq = (const float*)d_in[5];
  const float* Wk = (const float*)d_in[6];
  const float* bk = (const float*)d_in[7];
  const float* Wv = (const float*)d_in[8];
  const float* bv = (const float*)d_in[9];
  const float* Wo = (const float*)d_in[10];
  const float* bo = (const float*)d_in[11];
  float* out = (float*)d_out;
  unsigned short* wt = (unsigned short*)d_ws;  // 4 x 512x512 bf16 = 2 MB

  wtrans<<<dim3(8, 8, 4), 256, 0, stream>>>(Wq, Wk, Wv, Wo, wt);
  fused_attn<<<2048, 512, 0, stream>>>(q, k, v, mask, wt, bq, bk, bv, bo, out);
}